// Round 4
// baseline (223.280 us; speedup 1.0000x reference)
//
#include <hip/hip_runtime.h>
#include <math.h>

#define Bc 4
#define Tc 1024
#define Dc 256
#define Hc 8
#define Cc 16
#define LUTN 256

typedef __attribute__((ext_vector_type(8))) short short8;
typedef __attribute__((ext_vector_type(4))) float f32x4;

__device__ __forceinline__ unsigned bf16u(float x) {
    unsigned u = __float_as_uint(x);
    return (u + 0x7FFFu + ((u >> 16) & 1u)) >> 16;
}
__device__ __forceinline__ unsigned pk2(float lo, float hi) {
    return bf16u(lo) | (bf16u(hi) << 16);
}

// ---------------- K-1: cast x and all weights to bf16 ----------------------
// x: 1048576 | Wq,Wk,Wv: 65536 each -> Wqkvc[768][256] | Wo -> Woc | Wf -> Wfc
__global__ __launch_bounds__(256) void cast_all(
    const float* __restrict__ x,
    const float* __restrict__ Wq, const float* __restrict__ Wk,
    const float* __restrict__ Wv, const float* __restrict__ Wo,
    const float* __restrict__ Wf,
    ushort* __restrict__ Xc, ushort* __restrict__ Wqkvc,
    ushort* __restrict__ Woc, ushort* __restrict__ Wfc)
{
    const int e = (blockIdx.x * 256 + threadIdx.x) * 4;
    const float* src; ushort* dst; int off;
    if (e < 1048576)      { src = x;  dst = Xc;            off = e; }
    else if (e < 1114112) { src = Wq; dst = Wqkvc;         off = e - 1048576; }
    else if (e < 1179648) { src = Wk; dst = Wqkvc + 65536; off = e - 1114112; }
    else if (e < 1245184) { src = Wv; dst = Wqkvc + 131072; off = e - 1179648; }
    else if (e < 1310720) { src = Wo; dst = Woc;           off = e - 1245184; }
    else                  { src = Wf; dst = Wfc;           off = e - 1310720; }
    float4 v = *(const float4*)(src + off);
    uint2 p; p.x = pk2(v.x, v.y); p.y = pk2(v.z, v.w);
    *(uint2*)(dst + off) = p;
}

// ---------------- K0: PWL LUT, bf16-packed [hg][bin][(a,b) x 4 heads] -------
__global__ __launch_bounds__(256) void lut_build(
    const float* __restrict__ pw1, const float* __restrict__ pb1,
    const float* __restrict__ pw2, const float* __restrict__ pb2,
    ushort* __restrict__ LUTb)
{
    const int bin = threadIdx.x;
    const float d0 = bin * (1.f / LUTN), d1 = (bin + 1) * (1.f / LUTN);
    for (int h = 0; h < Hc; ++h) {
        float y0 = pb2[h], y1 = pb2[h];
#pragma unroll
        for (int c = 0; c < Cc; ++c) {
            float w1 = pw1[h * Cc + c], b1 = pb1[h * Cc + c], w2 = pw2[h * Cc + c];
            float h0 = fmaf(w1, d0, b1), h1 = fmaf(w1, d1, b1);
            y0 = fmaf(w2, h0 >= 0.f ? h0 : 0.01f * h0, y0);
            y1 = fmaf(w2, h1 >= 0.f ? h1 : 0.01f * h1, y1);
        }
        float a = (y1 - y0) * (float)LUTN;
        float b = y0 - a * d0;
        LUTb[(h >> 2) * 2048 + bin * 8 + (h & 3) * 2]     = (ushort)bf16u(a);
        LUTb[(h >> 2) * 2048 + bin * 8 + (h & 3) * 2 + 1] = (ushort)bf16u(b);
    }
}

// ---------------- bf16 MFMA GEMM: C[4096 x N] = A[4096 x 256] . W[N x 256]^T
// mode 0: N=768 QKV -> Qb/Kb (l2norm) + Vt transposed
// mode 1: N=256, +bias -> fp32 out
// mode 2: N=256, +bias +lrelu -> fp32 out
#define XS 72

__global__ __launch_bounds__(256) void gemm_mfma(
    const ushort* __restrict__ A, const ushort* __restrict__ W,
    const float* __restrict__ bias, float* __restrict__ outF,
    ushort* __restrict__ Qb, ushort* __restrict__ Kb, ushort* __restrict__ Vt,
    int mode)
{
    const int tid = threadIdx.x;
    const int wv = tid >> 6;
    const int wm = wv >> 1, wn = wv & 1;
    const int l = tid & 63;
    const int u = l & 15, g = l >> 4;
    const int rbase = blockIdx.x * 64;
    const int cbase = blockIdx.y * 64;

    __shared__ __align__(16) ushort As[64][XS];
    __shared__ __align__(16) ushort Ws[64][XS];

    f32x4 acc[2][2];
#pragma unroll
    for (int i = 0; i < 2; ++i)
#pragma unroll
        for (int j = 0; j < 2; ++j) acc[i][j] = (f32x4){0.f, 0.f, 0.f, 0.f};

    const int srow = tid >> 2;
    const int scol = (tid & 3) * 16;

    for (int k0 = 0; k0 < 256; k0 += 64) {
        uint4 xa = *(const uint4*)(A + (size_t)(rbase + srow) * 256 + k0 + scol);
        uint4 xb = *(const uint4*)(A + (size_t)(rbase + srow) * 256 + k0 + scol + 8);
        uint4 wa = *(const uint4*)(W + (size_t)(cbase + srow) * 256 + k0 + scol);
        uint4 wb = *(const uint4*)(W + (size_t)(cbase + srow) * 256 + k0 + scol + 8);
        __syncthreads();          // previous-stage frag reads done
        *(uint4*)&As[srow][scol]     = xa;
        *(uint4*)&As[srow][scol + 8] = xb;
        *(uint4*)&Ws[srow][scol]     = wa;
        *(uint4*)&Ws[srow][scol + 8] = wb;
        __syncthreads();
#pragma unroll
        for (int kk = 0; kk < 64; kk += 32) {
            short8 af0 = *(const short8*)&As[wm * 32 + u][kk + g * 8];
            short8 af1 = *(const short8*)&As[wm * 32 + 16 + u][kk + g * 8];
            short8 bf0 = *(const short8*)&Ws[wn * 32 + u][kk + g * 8];
            short8 bf1 = *(const short8*)&Ws[wn * 32 + 16 + u][kk + g * 8];
            acc[0][0] = __builtin_amdgcn_mfma_f32_16x16x32_bf16(af0, bf0, acc[0][0], 0, 0, 0);
            acc[0][1] = __builtin_amdgcn_mfma_f32_16x16x32_bf16(af0, bf1, acc[0][1], 0, 0, 0);
            acc[1][0] = __builtin_amdgcn_mfma_f32_16x16x32_bf16(af1, bf0, acc[1][0], 0, 0, 0);
            acc[1][1] = __builtin_amdgcn_mfma_f32_16x16x32_bf16(af1, bf1, acc[1][1], 0, 0, 0);
        }
    }

    if (mode == 0) {
        const int F0 = cbase + wn * 32;       // multiple of 32
        const int mat = F0 >> 8;
        const int head = (F0 & 255) >> 5;
        const int tb = rbase + wm * 32;
        if (mat < 2) {
            ushort* Out = (mat == 0) ? Qb : Kb;
#pragma unroll
            for (int mt = 0; mt < 2; ++mt)
#pragma unroll
                for (int reg = 0; reg < 4; ++reg) {
                    float ss = acc[mt][0][reg] * acc[mt][0][reg]
                             + acc[mt][1][reg] * acc[mt][1][reg];
                    ss += __shfl_xor(ss, 1, 64);
                    ss += __shfl_xor(ss, 2, 64);
                    ss += __shfl_xor(ss, 4, 64);
                    ss += __shfl_xor(ss, 8, 64);
                    float scn = 1.f / fmaxf(sqrtf(ss), 1e-12f);
                    const int t = tb + mt * 16 + 4 * g + reg;
                    const int bb = t >> 10, tt = t & 1023;
                    const size_t base = ((size_t)(bb * 8 + head) * Tc + tt) * 32;
                    Out[base + u]      = (ushort)bf16u(acc[mt][0][reg] * scn);
                    Out[base + 16 + u] = (ushort)bf16u(acc[mt][1][reg] * scn);
                }
        } else {
#pragma unroll
            for (int mt = 0; mt < 2; ++mt)
#pragma unroll
                for (int reg = 0; reg < 4; ++reg) {
                    const int t = tb + mt * 16 + 4 * g + reg;
                    const int bb = t >> 10, tt = t & 1023;
#pragma unroll
                    for (int nt = 0; nt < 2; ++nt) {
                        const int dk = nt * 16 + u;
                        Vt[((size_t)(bb * 8 + head) * 32 + dk) * Tc + tt] =
                            (ushort)bf16u(acc[mt][nt][reg]);
                    }
                }
        }
    } else {
#pragma unroll
        for (int nt = 0; nt < 2; ++nt) {
            const int col = cbase + wn * 32 + nt * 16 + u;
            const float bv = bias[col];
#pragma unroll
            for (int mt = 0; mt < 2; ++mt)
#pragma unroll
                for (int reg = 0; reg < 4; ++reg) {
                    const int row = rbase + wm * 32 + mt * 16 + 4 * g + reg;
                    float v = acc[mt][nt][reg] + bv;
                    if (mode == 2) v = v >= 0.f ? v : 0.01f * v;
                    outF[(size_t)row * Dc + col] = v;
                }
        }
    }
}

// ---------------- K2: MFMA flash attention ---------------------------------
// grid (T/16, B, 2). block 512 = 8 waves, each wave: 16 t x 4 heads x 128 s.
__global__ __launch_bounds__(512) void attn_mfma(
    const ushort* __restrict__ Qb, const ushort* __restrict__ Kb,
    const ushort* __restrict__ Vt,
    const float* __restrict__ rel, const int* __restrict__ msk,
    const ushort* __restrict__ LUTb,
    ushort* __restrict__ Yb)
{
    const int tid = threadIdx.x;
    const int w = tid >> 6;
    const int l = tid & 63;
    const int u = l & 15;
    const int g = l >> 4;
    const int t0 = blockIdx.x * 16;
    const int b = blockIdx.y;
    const int hg = blockIdx.z;

    __shared__ __align__(16) ushort lut_s[2048];     // [bin][(a,b) x 4 heads] bf16
    __shared__ __align__(16) unsigned plds[8 * 320]; // per-wave P scratch
    __shared__ __align__(16) float comb[16 * 132];   // [t][4h x 32v + pad]
    __shared__ float rs_g[64];                       // [hi][t]

    // stage LUT (4 KB) + zero accumulators
    *(uint2*)(lut_s + tid * 4) = *(const uint2*)(LUTb + hg * 2048 + tid * 4);
    for (int i = tid; i < 2112; i += 512) comb[i] = 0.f;
    if (tid < 64) rs_g[tid] = 0.f;

    const int bh0 = b * 8 + hg * 4;
    short8 qf[4];
#pragma unroll
    for (int hi = 0; hi < 4; ++hi)
        qf[hi] = *(const short8*)(Qb + (((size_t)(bh0 + hi) * Tc + t0 + u) * 32 + g * 8));

    f32x4 oacc[4][2];
#pragma unroll
    for (int hi = 0; hi < 4; ++hi)
#pragma unroll
        for (int vt = 0; vt < 2; ++vt)
            oacc[hi][vt] = (f32x4){0.f, 0.f, 0.f, 0.f};
    float rs[4][4];
#pragma unroll
    for (int hi = 0; hi < 4; ++hi)
#pragma unroll
        for (int reg = 0; reg < 4; ++reg) rs[hi][reg] = 0.f;

    unsigned* pwb = plds + w * 320;
    const size_t dbase = (size_t)b * Tc * Tc;

    __syncthreads();

    const int s_begin = w * 128;
    for (int sc = s_begin; sc < s_begin + 128; sc += 32) {
        float dA[4], dB[4];
#pragma unroll
        for (int reg = 0; reg < 4; ++reg) {
            const int t = t0 + 4 * g + reg;
            const size_t off = dbase + (size_t)t * Tc + sc + 2 * u;
            float2 d2 = *(const float2*)(rel + off);
            int2 m2 = *(const int2*)(msk + off);
            dA[reg] = m2.x ? -1.f : d2.x;
            dB[reg] = m2.y ? -1.f : d2.y;
        }
        float biasA[4][4], biasB[4][4];
#pragma unroll
        for (int reg = 0; reg < 4; ++reg) {
            int iA = (int)(dA[reg] * (float)LUTN);
            int iB = (int)(dB[reg] * (float)LUTN);
            iA = iA < 0 ? 0 : (iA > LUTN - 1 ? LUTN - 1 : iA);
            iB = iB < 0 ? 0 : (iB > LUTN - 1 ? LUTN - 1 : iB);
            uint4 wA = *(const uint4*)(lut_s + iA * 8);
            uint4 wB = *(const uint4*)(lut_s + iB * 8);
            biasA[reg][0] = fmaf(__uint_as_float(wA.x << 16), dA[reg], __uint_as_float(wA.x & 0xffff0000u));
            biasA[reg][1] = fmaf(__uint_as_float(wA.y << 16), dA[reg], __uint_as_float(wA.y & 0xffff0000u));
            biasA[reg][2] = fmaf(__uint_as_float(wA.z << 16), dA[reg], __uint_as_float(wA.z & 0xffff0000u));
            biasA[reg][3] = fmaf(__uint_as_float(wA.w << 16), dA[reg], __uint_as_float(wA.w & 0xffff0000u));
            biasB[reg][0] = fmaf(__uint_as_float(wB.x << 16), dB[reg], __uint_as_float(wB.x & 0xffff0000u));
            biasB[reg][1] = fmaf(__uint_as_float(wB.y << 16), dB[reg], __uint_as_float(wB.y & 0xffff0000u));
            biasB[reg][2] = fmaf(__uint_as_float(wB.z << 16), dB[reg], __uint_as_float(wB.z & 0xffff0000u));
            biasB[reg][3] = fmaf(__uint_as_float(wB.w << 16), dB[reg], __uint_as_float(wB.w & 0xffff0000u));
        }
#pragma unroll
        for (int hi = 0; hi < 4; ++hi) {
            const size_t kb = ((size_t)(bh0 + hi) * Tc + sc + 2 * u) * 32 + g * 8;
            short8 kfA = *(const short8*)(Kb + kb);
            short8 kfB = *(const short8*)(Kb + kb + 32);
            const f32x4 z4 = (f32x4){0.f, 0.f, 0.f, 0.f};
            f32x4 sA = __builtin_amdgcn_mfma_f32_16x16x32_bf16(qf[hi], kfA, z4, 0, 0, 0);
            f32x4 sB = __builtin_amdgcn_mfma_f32_16x16x32_bf16(qf[hi], kfB, z4, 0, 0, 0);
#pragma unroll
            for (int reg = 0; reg < 4; ++reg) {
                float zA = (dA[reg] < 0.f) ? 0.f : __expf(sA[reg] - biasA[reg][hi]);
                float zB = (dB[reg] < 0.f) ? 0.f : __expf(sB[reg] - biasB[reg][hi]);
                rs[hi][reg] += zA + zB;
                pwb[(4 * g + reg) * 20 + u] = pk2(zA, zB);
            }
            short8 pf = *(const short8*)((const char*)pwb + u * 80 + g * 16);
            const size_t vb = ((size_t)(bh0 + hi) * 32 + u) * Tc + sc + g * 8;
            short8 vf0 = *(const short8*)(Vt + vb);
            short8 vf1 = *(const short8*)(Vt + vb + (size_t)16 * Tc);
            oacc[hi][0] = __builtin_amdgcn_mfma_f32_16x16x32_bf16(pf, vf0, oacc[hi][0], 0, 0, 0);
            oacc[hi][1] = __builtin_amdgcn_mfma_f32_16x16x32_bf16(pf, vf1, oacc[hi][1], 0, 0, 0);
        }
    }

    // reduce row-sums over the 16 s-lanes, accumulate into shared
#pragma unroll
    for (int hi = 0; hi < 4; ++hi)
#pragma unroll
        for (int reg = 0; reg < 4; ++reg) {
            float v = rs[hi][reg];
            v += __shfl_xor(v, 1, 64);
            v += __shfl_xor(v, 2, 64);
            v += __shfl_xor(v, 4, 64);
            v += __shfl_xor(v, 8, 64);
            if (u == 0) atomicAdd(&rs_g[hi * 16 + 4 * g + reg], v);
        }
#pragma unroll
    for (int hi = 0; hi < 4; ++hi)
#pragma unroll
        for (int vt = 0; vt < 2; ++vt)
#pragma unroll
            for (int reg = 0; reg < 4; ++reg)
                atomicAdd(&comb[(4 * g + reg) * 132 + hi * 32 + vt * 16 + u],
                          oacc[hi][vt][reg]);
    __syncthreads();

    // normalize + store bf16 Y
    const int tl = tid >> 5;          // 0..15
    const int fq = tid & 31;          // 0..31
    const int f0 = fq * 4;            // 0..124
    const int hl = f0 >> 5;
    float rstot = rs_g[hl * 16 + tl];
    float inv = 1.f / (rstot + 1e-5f);
    float4 o = *(const float4*)(comb + tl * 132 + f0);
    uint2 p;
    p.x = pk2(o.x * inv, o.y * inv);
    p.y = pk2(o.z * inv, o.w * inv);
    *(uint2*)(Yb + ((size_t)b * Tc + t0 + tl) * Dc + hg * 128 + f0) = p;
}

// ---------------- residual + LayerNorm (+ optional bf16 copy) ---------------
__global__ __launch_bounds__(256) void resid_ln_kernel(
    const float* __restrict__ y, const float* __restrict__ res,
    const float* __restrict__ g, const float* __restrict__ beta,
    float* __restrict__ out, ushort* __restrict__ outb)
{
    const int j = threadIdx.x;
    const int row = blockIdx.x;
    __shared__ float red[8];
    float s = y[(size_t)row * Dc + j] + res[(size_t)row * Dc + j];

    float s1 = s, s2 = s * s;
#pragma unroll
    for (int m = 32; m >= 1; m >>= 1) {
        s1 += __shfl_xor(s1, m, 64);
        s2 += __shfl_xor(s2, m, 64);
    }
    const int w = j >> 6;
    if ((j & 63) == 0) { red[w] = s1; red[w + 4] = s2; }
    __syncthreads();
    float S1 = red[0] + red[1] + red[2] + red[3];
    float S2 = red[4] + red[5] + red[6] + red[7];
    float mu = S1 * (1.f / Dc);
    float var = S2 * (1.f / Dc) - mu * mu;
    float o = (s - mu) * rsqrtf(var + 1e-5f) * g[j] + beta[j];
    out[(size_t)row * Dc + j] = o;
    if (outb) outb[(size_t)row * Dc + j] = (ushort)bf16u(o);
}

extern "C" void kernel_launch(void* const* d_in, const int* in_sizes, int n_in,
                              void* d_out, int out_size, void* d_ws, size_t ws_size,
                              hipStream_t stream) {
    const float* x    = (const float*)d_in[0];
    const int*   mask = (const int*)d_in[1];
    const float* rel  = (const float*)d_in[2];
    const float* Wq   = (const float*)d_in[3];
    const float* Wk   = (const float*)d_in[4];
    const float* Wv   = (const float*)d_in[5];
    const float* pw1  = (const float*)d_in[6];
    const float* pb1  = (const float*)d_in[7];
    const float* pw2  = (const float*)d_in[8];
    const float* pb2  = (const float*)d_in[9];
    const float* Wo   = (const float*)d_in[10];
    const float* bo   = (const float*)d_in[11];
    const float* Wf   = (const float*)d_in[12];
    const float* bf   = (const float*)d_in[13];
    const float* g1   = (const float*)d_in[14];
    const float* be1  = (const float*)d_in[15];
    const float* g2   = (const float*)d_in[16];
    const float* be2  = (const float*)d_in[17];
    float* out = (float*)d_out;

    char* wsb = (char*)d_ws;
    ushort* Xc    = (ushort*)(wsb);                        // 2 MB
    ushort* Qb    = (ushort*)(wsb + (size_t)( 2 << 20));   // 2 MB
    ushort* Kb    = (ushort*)(wsb + (size_t)( 4 << 20));   // 2 MB
    ushort* Vt    = (ushort*)(wsb + (size_t)( 6 << 20));   // 2 MB
    ushort* Yb    = (ushort*)(wsb + (size_t)( 8 << 20));   // 2 MB
    ushort* Wqkvc = (ushort*)(wsb + (size_t)(10 << 20));   // 384 KB
    ushort* Woc   = (ushort*)(wsb + (size_t)(10 << 20) + (512 << 10));  // 128 KB
    ushort* Wfc   = (ushort*)(wsb + (size_t)(10 << 20) + (768 << 10));  // 128 KB
    ushort* LUTb  = (ushort*)(wsb + (size_t)(11 << 20));   // 8 KB
    float*  PY    = (float*)(wsb + (size_t)(12 << 20));    // 4 MB
    float*  ZZ    = (float*)(wsb + (size_t)(16 << 20));    // 4 MB
    ushort* ZZb   = (ushort*)(wsb + (size_t)(20 << 20));   // 2 MB
    float*  FY    = (float*)(wsb + (size_t)(22 << 20));    // 4 MB

    cast_all<<<1344, 256, 0, stream>>>(x, Wq, Wk, Wv, Wo, Wf, Xc, Wqkvc, Woc, Wfc);
    lut_build<<<1, 256, 0, stream>>>(pw1, pb1, pw2, pb2, LUTb);
    gemm_mfma<<<dim3(64, 12), 256, 0, stream>>>(Xc, Wqkvc, nullptr, nullptr,
                                                Qb, Kb, Vt, 0);
    attn_mfma<<<dim3(64, 4, 2), 512, 0, stream>>>(Qb, Kb, Vt, rel, mask, LUTb, Yb);
    gemm_mfma<<<dim3(64, 4), 256, 0, stream>>>(Yb, Woc, bo, PY,
                                               nullptr, nullptr, nullptr, 1);
    resid_ln_kernel<<<4096, 256, 0, stream>>>(PY, x, g1, be1, ZZ, ZZb);
    gemm_mfma<<<dim3(64, 4), 256, 0, stream>>>(ZZb, Wfc, bf, FY,
                                               nullptr, nullptr, nullptr, 2);
    resid_ln_kernel<<<4096, 256, 0, stream>>>(FY, ZZ, g2, be2, out, nullptr);
}

// Round 5
// 194.292 us; speedup vs baseline: 1.1492x; 1.1492x over previous
//
#include <hip/hip_runtime.h>
#include <math.h>

#define Bc 4
#define Tc 1024
#define Dc 256
#define Hc 8
#define Cc 16
#define LUTN 256

typedef __attribute__((ext_vector_type(8))) short short8;
typedef __attribute__((ext_vector_type(4))) float f32x4;

__device__ __forceinline__ unsigned bf16u(float x) {
    unsigned u = __float_as_uint(x);
    return (u + 0x7FFFu + ((u >> 16) & 1u)) >> 16;
}
__device__ __forceinline__ unsigned pk2(float lo, float hi) {
    return bf16u(lo) | (bf16u(hi) << 16);
}
__device__ __forceinline__ float upk(unsigned v) {     // low half
    return __uint_as_float(v << 16);
}
__device__ __forceinline__ float upkh(unsigned v) {    // high half
    return __uint_as_float(v & 0xffff0000u);
}

// ---------------- K0: cast x + weights to bf16, block 1344 builds the LUT ---
__global__ __launch_bounds__(256) void cast_all(
    const float* __restrict__ x,
    const float* __restrict__ Wq, const float* __restrict__ Wk,
    const float* __restrict__ Wv, const float* __restrict__ Wo,
    const float* __restrict__ Wf,
    const float* __restrict__ pw1, const float* __restrict__ pb1,
    const float* __restrict__ pw2, const float* __restrict__ pb2,
    ushort* __restrict__ Xc, ushort* __restrict__ Wqkvc,
    ushort* __restrict__ Woc, ushort* __restrict__ Wfc,
    ushort* __restrict__ LUTb)
{
    if (blockIdx.x == 1344) {
        // PWL LUT: bias(h,d) ~= a*d+b per 1/256 bin; layout [hg][bin][(a,b)x4h]
        const int bin = threadIdx.x;
        const float d0 = bin * (1.f / LUTN), d1 = (bin + 1) * (1.f / LUTN);
        for (int h = 0; h < Hc; ++h) {
            float y0 = pb2[h], y1 = pb2[h];
#pragma unroll
            for (int c = 0; c < Cc; ++c) {
                float w1 = pw1[h * Cc + c], b1 = pb1[h * Cc + c], w2 = pw2[h * Cc + c];
                float h0 = fmaf(w1, d0, b1), h1 = fmaf(w1, d1, b1);
                y0 = fmaf(w2, h0 >= 0.f ? h0 : 0.01f * h0, y0);
                y1 = fmaf(w2, h1 >= 0.f ? h1 : 0.01f * h1, y1);
            }
            float a = (y1 - y0) * (float)LUTN;
            float b = y0 - a * d0;
            LUTb[(h >> 2) * 2048 + bin * 8 + (h & 3) * 2]     = (ushort)bf16u(a);
            LUTb[(h >> 2) * 2048 + bin * 8 + (h & 3) * 2 + 1] = (ushort)bf16u(b);
        }
        return;
    }
    const int e = (blockIdx.x * 256 + threadIdx.x) * 4;
    const float* src; ushort* dst; int off;
    if (e < 1048576)      { src = x;  dst = Xc;             off = e; }
    else if (e < 1114112) { src = Wq; dst = Wqkvc;          off = e - 1048576; }
    else if (e < 1179648) { src = Wk; dst = Wqkvc + 65536;  off = e - 1114112; }
    else if (e < 1245184) { src = Wv; dst = Wqkvc + 131072; off = e - 1179648; }
    else if (e < 1310720) { src = Wo; dst = Woc;            off = e - 1245184; }
    else                  { src = Wf; dst = Wfc;            off = e - 1310720; }
    float4 v = *(const float4*)(src + off);
    uint2 p; p.x = pk2(v.x, v.y); p.y = pk2(v.z, v.w);
    *(uint2*)(dst + off) = p;
}

// ---------------- bf16 MFMA GEMM -------------------------------------------
// mode 0: N=768 QKV -> Qb/Kb (l2norm) + Vt transposed
// mode 1: N=256 +bias -> fp32   mode 2: N=256 +bias +lrelu -> fp32
#define XS 72

__global__ __launch_bounds__(256) void gemm_mfma(
    const ushort* __restrict__ A, const ushort* __restrict__ W,
    const float* __restrict__ bias, float* __restrict__ outF,
    ushort* __restrict__ Qb, ushort* __restrict__ Kb, ushort* __restrict__ Vt,
    int mode)
{
    const int tid = threadIdx.x;
    const int wv = tid >> 6;
    const int wm = wv >> 1, wn = wv & 1;
    const int l = tid & 63;
    const int u = l & 15, g = l >> 4;
    const int rbase = blockIdx.x * 64;
    const int cbase = blockIdx.y * 64;

    __shared__ __align__(16) ushort As[64][XS];
    __shared__ __align__(16) ushort Ws[64][XS];

    f32x4 acc[2][2];
#pragma unroll
    for (int i = 0; i < 2; ++i)
#pragma unroll
        for (int j = 0; j < 2; ++j) acc[i][j] = (f32x4){0.f, 0.f, 0.f, 0.f};

    const int srow = tid >> 2;
    const int scol = (tid & 3) * 16;

    for (int k0 = 0; k0 < 256; k0 += 64) {
        uint4 xa = *(const uint4*)(A + (size_t)(rbase + srow) * 256 + k0 + scol);
        uint4 xb = *(const uint4*)(A + (size_t)(rbase + srow) * 256 + k0 + scol + 8);
        uint4 wa = *(const uint4*)(W + (size_t)(cbase + srow) * 256 + k0 + scol);
        uint4 wb = *(const uint4*)(W + (size_t)(cbase + srow) * 256 + k0 + scol + 8);
        __syncthreads();
        *(uint4*)&As[srow][scol]     = xa;
        *(uint4*)&As[srow][scol + 8] = xb;
        *(uint4*)&Ws[srow][scol]     = wa;
        *(uint4*)&Ws[srow][scol + 8] = wb;
        __syncthreads();
#pragma unroll
        for (int kk = 0; kk < 64; kk += 32) {
            short8 af0 = *(const short8*)&As[wm * 32 + u][kk + g * 8];
            short8 af1 = *(const short8*)&As[wm * 32 + 16 + u][kk + g * 8];
            short8 bf0 = *(const short8*)&Ws[wn * 32 + u][kk + g * 8];
            short8 bf1 = *(const short8*)&Ws[wn * 32 + 16 + u][kk + g * 8];
            acc[0][0] = __builtin_amdgcn_mfma_f32_16x16x32_bf16(af0, bf0, acc[0][0], 0, 0, 0);
            acc[0][1] = __builtin_amdgcn_mfma_f32_16x16x32_bf16(af0, bf1, acc[0][1], 0, 0, 0);
            acc[1][0] = __builtin_amdgcn_mfma_f32_16x16x32_bf16(af1, bf0, acc[1][0], 0, 0, 0);
            acc[1][1] = __builtin_amdgcn_mfma_f32_16x16x32_bf16(af1, bf1, acc[1][1], 0, 0, 0);
        }
    }

    if (mode == 0) {
        const int F0 = cbase + wn * 32;
        const int mat = F0 >> 8;
        const int head = (F0 & 255) >> 5;
        const int tb = rbase + wm * 32;
        if (mat < 2) {
            ushort* Out = (mat == 0) ? Qb : Kb;
#pragma unroll
            for (int mt = 0; mt < 2; ++mt)
#pragma unroll
                for (int reg = 0; reg < 4; ++reg) {
                    float ss = acc[mt][0][reg] * acc[mt][0][reg]
                             + acc[mt][1][reg] * acc[mt][1][reg];
                    ss += __shfl_xor(ss, 1, 64);
                    ss += __shfl_xor(ss, 2, 64);
                    ss += __shfl_xor(ss, 4, 64);
                    ss += __shfl_xor(ss, 8, 64);
                    float scn = 1.f / fmaxf(sqrtf(ss), 1e-12f);
                    const int t = tb + mt * 16 + 4 * g + reg;
                    const int bb = t >> 10, tt = t & 1023;
                    const size_t base = ((size_t)(bb * 8 + head) * Tc + tt) * 32;
                    Out[base + u]      = (ushort)bf16u(acc[mt][0][reg] * scn);
                    Out[base + 16 + u] = (ushort)bf16u(acc[mt][1][reg] * scn);
                }
        } else {
#pragma unroll
            for (int mt = 0; mt < 2; ++mt)
#pragma unroll
                for (int reg = 0; reg < 4; ++reg) {
                    const int t = tb + mt * 16 + 4 * g + reg;
                    const int bb = t >> 10, tt = t & 1023;
#pragma unroll
                    for (int nt = 0; nt < 2; ++nt) {
                        const int dk = nt * 16 + u;
                        Vt[((size_t)(bb * 8 + head) * 32 + dk) * Tc + tt] =
                            (ushort)bf16u(acc[mt][nt][reg]);
                    }
                }
        }
    } else {
#pragma unroll
        for (int nt = 0; nt < 2; ++nt) {
            const int col = cbase + wn * 32 + nt * 16 + u;
            const float bv = bias[col];
#pragma unroll
            for (int mt = 0; mt < 2; ++mt)
#pragma unroll
                for (int reg = 0; reg < 4; ++reg) {
                    const int row = rbase + wm * 32 + mt * 16 + 4 * g + reg;
                    float v = acc[mt][nt][reg] + bv;
                    if (mode == 2) v = v >= 0.f ? v : 0.01f * v;
                    outF[(size_t)row * Dc + col] = v;
                }
        }
    }
}

// ---------------- K2: MFMA flash attention, s-split across blocks -----------
// grid (T/16, B, 8): z = hg*4 + split. 256 threads = 4 waves; wave w covers
// s in [split*256 + w*64, +64). Emits bf16 O-partials + fp32 rowsums.
__global__ __launch_bounds__(256) void attn_split(
    const ushort* __restrict__ Qb, const ushort* __restrict__ Kb,
    const ushort* __restrict__ Vt,
    const float* __restrict__ rel, const int* __restrict__ msk,
    const ushort* __restrict__ LUTb,
    ushort* __restrict__ Opart, float* __restrict__ RSg)
{
    const int tid = threadIdx.x;
    const int w = tid >> 6;
    const int l = tid & 63;
    const int u = l & 15;
    const int g = l >> 4;
    const int t0 = blockIdx.x * 16;
    const int b = blockIdx.y;
    const int hg = blockIdx.z >> 2;
    const int sp = blockIdx.z & 3;

    __shared__ __align__(16) ushort lut_s[2048];      // 4 KB
    __shared__ __align__(16) unsigned plds[4 * 320];  // 5 KB P scratch
    __shared__ __align__(16) ushort comb[4 * 16 * 136]; // 17 KB bf16 partials
    __shared__ float rs_s[4 * 64];                    // 1 KB

    *(uint4*)(lut_s + tid * 8) = *(const uint4*)(LUTb + hg * 2048 + tid * 8);

    const int bh0 = b * 8 + hg * 4;
    short8 qf[4];
#pragma unroll
    for (int hi = 0; hi < 4; ++hi)
        qf[hi] = *(const short8*)(Qb + (((size_t)(bh0 + hi) * Tc + t0 + u) * 32 + g * 8));

    f32x4 oacc[4][2];
#pragma unroll
    for (int hi = 0; hi < 4; ++hi)
#pragma unroll
        for (int vt = 0; vt < 2; ++vt)
            oacc[hi][vt] = (f32x4){0.f, 0.f, 0.f, 0.f};
    float rs[4][4];
#pragma unroll
    for (int hi = 0; hi < 4; ++hi)
#pragma unroll
        for (int reg = 0; reg < 4; ++reg) rs[hi][reg] = 0.f;

    unsigned* pwb = plds + w * 320;
    const size_t dbase = (size_t)b * Tc * Tc;

    __syncthreads();

    const int s_begin = sp * 256 + w * 64;
#pragma unroll
    for (int ch = 0; ch < 2; ++ch) {
        const int sc = s_begin + ch * 32;
        float dA[4], dB[4];
#pragma unroll
        for (int reg = 0; reg < 4; ++reg) {
            const int t = t0 + 4 * g + reg;
            const size_t off = dbase + (size_t)t * Tc + sc + 2 * u;
            float2 d2 = *(const float2*)(rel + off);
            int2 m2 = *(const int2*)(msk + off);
            dA[reg] = m2.x ? -1.f : d2.x;
            dB[reg] = m2.y ? -1.f : d2.y;
        }
        float biasA[4][4], biasB[4][4];
#pragma unroll
        for (int reg = 0; reg < 4; ++reg) {
            int iA = (int)(dA[reg] * (float)LUTN);
            int iB = (int)(dB[reg] * (float)LUTN);
            iA = iA < 0 ? 0 : (iA > LUTN - 1 ? LUTN - 1 : iA);
            iB = iB < 0 ? 0 : (iB > LUTN - 1 ? LUTN - 1 : iB);
            uint4 wA = *(const uint4*)(lut_s + iA * 8);
            uint4 wB = *(const uint4*)(lut_s + iB * 8);
            biasA[reg][0] = fmaf(upk(wA.x), dA[reg], upkh(wA.x));
            biasA[reg][1] = fmaf(upk(wA.y), dA[reg], upkh(wA.y));
            biasA[reg][2] = fmaf(upk(wA.z), dA[reg], upkh(wA.z));
            biasA[reg][3] = fmaf(upk(wA.w), dA[reg], upkh(wA.w));
            biasB[reg][0] = fmaf(upk(wB.x), dB[reg], upkh(wB.x));
            biasB[reg][1] = fmaf(upk(wB.y), dB[reg], upkh(wB.y));
            biasB[reg][2] = fmaf(upk(wB.z), dB[reg], upkh(wB.z));
            biasB[reg][3] = fmaf(upk(wB.w), dB[reg], upkh(wB.w));
        }
#pragma unroll
        for (int hi = 0; hi < 4; ++hi) {
            const size_t kb = ((size_t)(bh0 + hi) * Tc + sc + 2 * u) * 32 + g * 8;
            short8 kfA = *(const short8*)(Kb + kb);
            short8 kfB = *(const short8*)(Kb + kb + 32);
            const f32x4 z4 = (f32x4){0.f, 0.f, 0.f, 0.f};
            f32x4 sA = __builtin_amdgcn_mfma_f32_16x16x32_bf16(qf[hi], kfA, z4, 0, 0, 0);
            f32x4 sB = __builtin_amdgcn_mfma_f32_16x16x32_bf16(qf[hi], kfB, z4, 0, 0, 0);
#pragma unroll
            for (int reg = 0; reg < 4; ++reg) {
                float zA = (dA[reg] < 0.f) ? 0.f : __expf(sA[reg] - biasA[reg][hi]);
                float zB = (dB[reg] < 0.f) ? 0.f : __expf(sB[reg] - biasB[reg][hi]);
                rs[hi][reg] += zA + zB;
                pwb[(4 * g + reg) * 20 + u] = pk2(zA, zB);
            }
            short8 pf = *(const short8*)((const char*)pwb + u * 80 + g * 16);
            const size_t vb = ((size_t)(bh0 + hi) * 32 + u) * Tc + sc + g * 8;
            short8 vf0 = *(const short8*)(Vt + vb);
            short8 vf1 = *(const short8*)(Vt + vb + (size_t)16 * Tc);
            oacc[hi][0] = __builtin_amdgcn_mfma_f32_16x16x32_bf16(pf, vf0, oacc[hi][0], 0, 0, 0);
            oacc[hi][1] = __builtin_amdgcn_mfma_f32_16x16x32_bf16(pf, vf1, oacc[hi][1], 0, 0, 0);
        }
    }

    // per-wave: reduce rowsums over 16 s-lanes; stash bf16 O partials
#pragma unroll
    for (int hi = 0; hi < 4; ++hi)
#pragma unroll
        for (int reg = 0; reg < 4; ++reg) {
            float v = rs[hi][reg];
            v += __shfl_xor(v, 1, 64);
            v += __shfl_xor(v, 2, 64);
            v += __shfl_xor(v, 4, 64);
            v += __shfl_xor(v, 8, 64);
            if (u == 0) rs_s[(w * 4 + hi) * 16 + 4 * g + reg] = v;
        }
#pragma unroll
    for (int hi = 0; hi < 4; ++hi)
#pragma unroll
        for (int vt = 0; vt < 2; ++vt)
#pragma unroll
            for (int reg = 0; reg < 4; ++reg)
                comb[w * 2176 + (4 * g + reg) * 136 + hi * 32 + vt * 16 + u] =
                    (ushort)bf16u(oacc[hi][vt][reg]);
    __syncthreads();

    // combine 4 waves -> global bf16 O partial
    const int tl = tid >> 4;
    const int f0 = (tid & 15) * 8;
    float o[8];
#pragma unroll
    for (int k = 0; k < 8; ++k) o[k] = 0.f;
#pragma unroll
    for (int ww = 0; ww < 4; ++ww) {
        uint4 pv = *(const uint4*)&comb[ww * 2176 + tl * 136 + f0];
        o[0] += upk(pv.x); o[1] += upkh(pv.x);
        o[2] += upk(pv.y); o[3] += upkh(pv.y);
        o[4] += upk(pv.z); o[5] += upkh(pv.z);
        o[6] += upk(pv.w); o[7] += upkh(pv.w);
    }
    uint4 pw;
    pw.x = pk2(o[0], o[1]); pw.y = pk2(o[2], o[3]);
    pw.z = pk2(o[4], o[5]); pw.w = pk2(o[6], o[7]);
    *(uint4*)(Opart + (((size_t)sp * Bc + b) * Tc + t0 + tl) * Dc + hg * 128 + f0) = pw;

    if (tid < 64) {
        const int hi = tid >> 4, tt = tid & 15;
        float v = rs_s[(0 + hi) * 16 + tt] + rs_s[(4 + hi) * 16 + tt]
                + rs_s[(8 + hi) * 16 + tt] + rs_s[(12 + hi) * 16 + tt];
        RSg[(((size_t)sp * Bc + b) * Hc + hg * 4 + hi) * Tc + t0 + tt] = v;
    }
}

// ---------------- K3: combine s-splits, normalize, emit bf16 Y --------------
__global__ __launch_bounds__(256) void attn_reduce(
    const ushort* __restrict__ Opart, const float* __restrict__ RSg,
    ushort* __restrict__ Yb)
{
    const int tid = threadIdx.x;
    const int row = blockIdx.x * 8 + (tid >> 5);
    const int f0 = (tid & 31) * 8;
    const int b = row >> 10, t = row & 1023;
    const int h = f0 >> 5;
    float rst = 0.f;
#pragma unroll
    for (int sp = 0; sp < 4; ++sp)
        rst += RSg[(((size_t)sp * Bc + b) * Hc + h) * Tc + t];
    const float inv = 1.f / (rst + 1e-5f);
    float o[8];
#pragma unroll
    for (int k = 0; k < 8; ++k) o[k] = 0.f;
#pragma unroll
    for (int sp = 0; sp < 4; ++sp) {
        uint4 pv = *(const uint4*)(Opart + (((size_t)sp * Bc + b) * Tc + t) * Dc + f0);
        o[0] += upk(pv.x); o[1] += upkh(pv.x);
        o[2] += upk(pv.y); o[3] += upkh(pv.y);
        o[4] += upk(pv.z); o[5] += upkh(pv.z);
        o[6] += upk(pv.w); o[7] += upkh(pv.w);
    }
    uint4 pw;
    pw.x = pk2(o[0] * inv, o[1] * inv); pw.y = pk2(o[2] * inv, o[3] * inv);
    pw.z = pk2(o[4] * inv, o[5] * inv); pw.w = pk2(o[6] * inv, o[7] * inv);
    *(uint4*)(Yb + (size_t)row * Dc + f0) = pw;
}

// ---------------- residual + LayerNorm (+ optional bf16 copy) ---------------
__global__ __launch_bounds__(256) void resid_ln_kernel(
    const float* __restrict__ y, const float* __restrict__ res,
    const float* __restrict__ g, const float* __restrict__ beta,
    float* __restrict__ out, ushort* __restrict__ outb)
{
    const int j = threadIdx.x;
    const int row = blockIdx.x;
    __shared__ float red[8];
    float s = y[(size_t)row * Dc + j] + res[(size_t)row * Dc + j];

    float s1 = s, s2 = s * s;
#pragma unroll
    for (int m = 32; m >= 1; m >>= 1) {
        s1 += __shfl_xor(s1, m, 64);
        s2 += __shfl_xor(s2, m, 64);
    }
    const int w = j >> 6;
    if ((j & 63) == 0) { red[w] = s1; red[w + 4] = s2; }
    __syncthreads();
    float S1 = red[0] + red[1] + red[2] + red[3];
    float S2 = red[4] + red[5] + red[6] + red[7];
    float mu = S1 * (1.f / Dc);
    float var = S2 * (1.f / Dc) - mu * mu;
    float o = (s - mu) * rsqrtf(var + 1e-5f) * g[j] + beta[j];
    out[(size_t)row * Dc + j] = o;
    if (outb) outb[(size_t)row * Dc + j] = (ushort)bf16u(o);
}

extern "C" void kernel_launch(void* const* d_in, const int* in_sizes, int n_in,
                              void* d_out, int out_size, void* d_ws, size_t ws_size,
                              hipStream_t stream) {
    const float* x    = (const float*)d_in[0];
    const int*   mask = (const int*)d_in[1];
    const float* rel  = (const float*)d_in[2];
    const float* Wq   = (const float*)d_in[3];
    const float* Wk   = (const float*)d_in[4];
    const float* Wv   = (const float*)d_in[5];
    const float* pw1  = (const float*)d_in[6];
    const float* pb1  = (const float*)d_in[7];
    const float* pw2  = (const float*)d_in[8];
    const float* pb2  = (const float*)d_in[9];
    const float* Wo   = (const float*)d_in[10];
    const float* bo   = (const float*)d_in[11];
    const float* Wf   = (const float*)d_in[12];
    const float* bf   = (const float*)d_in[13];
    const float* g1   = (const float*)d_in[14];
    const float* be1  = (const float*)d_in[15];
    const float* g2   = (const float*)d_in[16];
    const float* be2  = (const float*)d_in[17];
    float* out = (float*)d_out;

    char* wsb = (char*)d_ws;
    ushort* Xc    = (ushort*)(wsb);                        // 2 MB
    ushort* Qb    = (ushort*)(wsb + (size_t)( 2 << 20));   // 2 MB
    ushort* Kb    = (ushort*)(wsb + (size_t)( 4 << 20));   // 2 MB
    ushort* Vt    = (ushort*)(wsb + (size_t)( 6 << 20));   // 2 MB
    ushort* Yb    = (ushort*)(wsb + (size_t)( 8 << 20));   // 2 MB
    ushort* Wqkvc = (ushort*)(wsb + (size_t)(10 << 20));   // 384 KB
    ushort* Woc   = (ushort*)(wsb + (size_t)(10 << 20) + (512 << 10));  // 128 KB
    ushort* Wfc   = (ushort*)(wsb + (size_t)(10 << 20) + (768 << 10));  // 128 KB
    ushort* LUTb  = (ushort*)(wsb + (size_t)(11 << 20));   // 8 KB
    float*  PY    = (float*)(wsb + (size_t)(12 << 20));    // 4 MB
    float*  ZZ    = (float*)(wsb + (size_t)(16 << 20));    // 4 MB
    ushort* ZZb   = (ushort*)(wsb + (size_t)(20 << 20));   // 2 MB
    float*  FY    = (float*)(wsb + (size_t)(22 << 20));    // 4 MB
    ushort* Opart = (ushort*)(wsb + (size_t)(26 << 20));   // 8 MB (4 splits bf16)
    float*  RSg   = (float*)(wsb + (size_t)(34 << 20));    // 512 KB

    cast_all<<<1345, 256, 0, stream>>>(x, Wq, Wk, Wv, Wo, Wf,
                                       pw1, pb1, pw2, pb2,
                                       Xc, Wqkvc, Woc, Wfc, LUTb);
    gemm_mfma<<<dim3(64, 12), 256, 0, stream>>>(Xc, Wqkvc, nullptr, nullptr,
                                                Qb, Kb, Vt, 0);
    attn_split<<<dim3(64, 4, 8), 256, 0, stream>>>(Qb, Kb, Vt, rel, mask, LUTb,
                                                   Opart, RSg);
    attn_reduce<<<512, 256, 0, stream>>>(Opart, RSg, Yb);
    gemm_mfma<<<dim3(64, 4), 256, 0, stream>>>(Yb, Woc, bo, PY,
                                               nullptr, nullptr, nullptr, 1);
    resid_ln_kernel<<<4096, 256, 0, stream>>>(PY, x, g1, be1, ZZ, ZZb);
    gemm_mfma<<<dim3(64, 4), 256, 0, stream>>>(ZZb, Wfc, bf, FY,
                                               nullptr, nullptr, nullptr, 2);
    resid_ln_kernel<<<4096, 256, 0, stream>>>(FY, ZZ, g2, be2, out, nullptr);
}

// Round 6
// 174.387 us; speedup vs baseline: 1.2804x; 1.1141x over previous
//
#include <hip/hip_runtime.h>
#include <math.h>

#define Bc 4
#define Tc 1024
#define Dc 256
#define Hc 8
#define Cc 16
#define LUTN 256

typedef __attribute__((ext_vector_type(8))) short short8;
typedef __attribute__((ext_vector_type(4))) float f32x4;

__device__ __forceinline__ unsigned bf16u(float x) {   // RNE
    unsigned u = __float_as_uint(x);
    return (u + 0x7FFFu + ((u >> 16) & 1u)) >> 16;
}
__device__ __forceinline__ unsigned pk2(float lo, float hi) {
    return bf16u(lo) | (bf16u(hi) << 16);
}
__device__ __forceinline__ unsigned pk2t(float lo, float hi) {  // truncating, 1 inst
    return __builtin_amdgcn_perm(__float_as_uint(hi), __float_as_uint(lo), 0x07060302u);
}
__device__ __forceinline__ float upk(unsigned v) { return __uint_as_float(v << 16); }
__device__ __forceinline__ float upkh(unsigned v) { return __uint_as_float(v & 0xffff0000u); }

// ---------------- K0: cast x + weights to bf16; block 1344 builds PWL LUT ---
__global__ __launch_bounds__(256) void cast_all(
    const float* __restrict__ x,
    const float* __restrict__ Wq, const float* __restrict__ Wk,
    const float* __restrict__ Wv, const float* __restrict__ Wo,
    const float* __restrict__ Wf,
    const float* __restrict__ pw1, const float* __restrict__ pb1,
    const float* __restrict__ pw2, const float* __restrict__ pb2,
    ushort* __restrict__ Xc, ushort* __restrict__ Wqkvc,
    ushort* __restrict__ Woc, ushort* __restrict__ Wfc,
    ushort* __restrict__ LUTb)
{
    if (blockIdx.x == 1344) {
        const int bin = threadIdx.x;
        const float d0 = bin * (1.f / LUTN), d1 = (bin + 1) * (1.f / LUTN);
        for (int h = 0; h < Hc; ++h) {
            float y0 = pb2[h], y1 = pb2[h];
#pragma unroll
            for (int c = 0; c < Cc; ++c) {
                float w1 = pw1[h * Cc + c], b1 = pb1[h * Cc + c], w2 = pw2[h * Cc + c];
                float h0 = fmaf(w1, d0, b1), h1 = fmaf(w1, d1, b1);
                y0 = fmaf(w2, h0 >= 0.f ? h0 : 0.01f * h0, y0);
                y1 = fmaf(w2, h1 >= 0.f ? h1 : 0.01f * h1, y1);
            }
            float a = (y1 - y0) * (float)LUTN;
            float b = y0 - a * d0;
            LUTb[(h >> 2) * 2048 + bin * 8 + (h & 3) * 2]     = (ushort)bf16u(a);
            LUTb[(h >> 2) * 2048 + bin * 8 + (h & 3) * 2 + 1] = (ushort)bf16u(b);
        }
        return;
    }
    const int e = (blockIdx.x * 256 + threadIdx.x) * 4;
    const float* src; ushort* dst; int off;
    if (e < 1048576)      { src = x;  dst = Xc;             off = e; }
    else if (e < 1114112) { src = Wq; dst = Wqkvc;          off = e - 1048576; }
    else if (e < 1179648) { src = Wk; dst = Wqkvc + 65536;  off = e - 1114112; }
    else if (e < 1245184) { src = Wv; dst = Wqkvc + 131072; off = e - 1179648; }
    else if (e < 1310720) { src = Wo; dst = Woc;            off = e - 1245184; }
    else                  { src = Wf; dst = Wfc;            off = e - 1310720; }
    float4 v = *(const float4*)(src + off);
    uint2 p; p.x = pk2(v.x, v.y); p.y = pk2(v.z, v.w);
    *(uint2*)(dst + off) = p;
}

// ---------------- K1: QKV direct-MFMA GEMM (no LDS, no barriers) ------------
// grid (256, 3), block 256 = 4 waves. Wave: C tile 16 rows x 64 cols.
// Q,K: [bh][t][32] bf16 l2-normalized. V: tile-major [bh][s/32][vt][16v][32s].
__global__ __launch_bounds__(256) void qkv_direct(
    const ushort* __restrict__ Xc, const ushort* __restrict__ Wqkv,
    ushort* __restrict__ Qb, ushort* __restrict__ Kb, ushort* __restrict__ Vt)
{
    const int tid = threadIdx.x;
    const int w = tid >> 6;
    const int l = tid & 63;
    const int u = l & 15, g = l >> 4;
    const int rbase = blockIdx.x * 16;
    const int cb = (blockIdx.y * 4 + w) * 64;     // 0..704

    f32x4 acc[4];
#pragma unroll
    for (int nt = 0; nt < 4; ++nt) acc[nt] = (f32x4){0.f, 0.f, 0.f, 0.f};

    const ushort* arow = Xc + (size_t)(rbase + u) * 256 + g * 8;
#pragma unroll 2
    for (int k0 = 0; k0 < 256; k0 += 32) {
        short8 af = *(const short8*)(arow + k0);
#pragma unroll
        for (int nt = 0; nt < 4; ++nt) {
            short8 bfr = *(const short8*)(Wqkv + (size_t)(cb + nt * 16 + u) * 256 + k0 + g * 8);
            acc[nt] = __builtin_amdgcn_mfma_f32_16x16x32_bf16(af, bfr, acc[nt], 0, 0, 0);
        }
    }

    const int mat = cb >> 8;
    const int fcb = cb & 255;
    if (mat < 2) {
        ushort* Out = (mat == 0) ? Qb : Kb;
#pragma unroll
        for (int hp = 0; hp < 2; ++hp) {          // two heads per wave tile
            const int head = (fcb >> 5) + hp;
#pragma unroll
            for (int reg = 0; reg < 4; ++reg) {
                float ss = acc[2 * hp][reg] * acc[2 * hp][reg]
                         + acc[2 * hp + 1][reg] * acc[2 * hp + 1][reg];
                ss += __shfl_xor(ss, 1, 64);
                ss += __shfl_xor(ss, 2, 64);
                ss += __shfl_xor(ss, 4, 64);
                ss += __shfl_xor(ss, 8, 64);
                float scn = 1.f / fmaxf(sqrtf(ss), 1e-12f);
                const int t = rbase + 4 * g + reg;
                const int bb = t >> 10, tt = t & 1023;
                const size_t base = ((size_t)(bb * 8 + head) * Tc + tt) * 32;
                Out[base + u]      = (ushort)bf16u(acc[2 * hp][reg] * scn);
                Out[base + 16 + u] = (ushort)bf16u(acc[2 * hp + 1][reg] * scn);
            }
        }
    } else {
#pragma unroll
        for (int nt = 0; nt < 4; ++nt) {
            const int head = (fcb >> 5) + (nt >> 1);
            const int vt = nt & 1;
#pragma unroll
            for (int reg = 0; reg < 4; ++reg) {
                const int s = rbase + 4 * g + reg;
                const int bb = s >> 10, ss = s & 1023;
                const int bh = bb * 8 + head;
                Vt[(((size_t)bh * 32 + (ss >> 5)) * 2 + vt) * 512 + u * 32 + (ss & 31)] =
                    (ushort)bf16u(acc[nt][reg]);
            }
        }
    }
}

// ---------------- K2: MFMA flash attention (round-3 structure) --------------
// grid (T/16, B, 2). block 256 = 4 waves; wave w covers s in [w*256, +256).
__global__ __launch_bounds__(256) void attn_mfma(
    const ushort* __restrict__ Qb, const ushort* __restrict__ Kb,
    const ushort* __restrict__ Vt,
    const float* __restrict__ rel, const int* __restrict__ msk,
    const ushort* __restrict__ LUTb,
    ushort* __restrict__ Yb)
{
    const int tid = threadIdx.x;
    const int w = tid >> 6;
    const int l = tid & 63;
    const int u = l & 15;
    const int g = l >> 4;
    const int t0 = blockIdx.x * 16;
    const int b = blockIdx.y;
    const int hg = blockIdx.z;

    __shared__ __align__(16) ushort lut_s[2048];        // 4 KB
    __shared__ __align__(16) unsigned plds[4 * 320];    // 5 KB
    __shared__ __align__(16) ushort comb[4 * 16 * 136]; // 17 KB bf16 partials
    __shared__ float rs_s[4 * 64];                      // 1 KB

    *(uint4*)(lut_s + tid * 8) = *(const uint4*)(LUTb + hg * 2048 + tid * 8);

    const int bh0 = b * 8 + hg * 4;
    short8 qf[4];
#pragma unroll
    for (int hi = 0; hi < 4; ++hi)
        qf[hi] = *(const short8*)(Qb + (((size_t)(bh0 + hi) * Tc + t0 + u) * 32 + g * 8));

    const short8 ones = (short8){0x3F80, 0x3F80, 0x3F80, 0x3F80,
                                 0x3F80, 0x3F80, 0x3F80, 0x3F80};

    f32x4 oacc[4][2];
    f32x4 rsacc[4];
#pragma unroll
    for (int hi = 0; hi < 4; ++hi) {
        oacc[hi][0] = (f32x4){0.f, 0.f, 0.f, 0.f};
        oacc[hi][1] = (f32x4){0.f, 0.f, 0.f, 0.f};
        rsacc[hi]   = (f32x4){0.f, 0.f, 0.f, 0.f};
    }

    unsigned* pwb = plds + w * 320;
    const size_t dbase = (size_t)b * Tc * Tc;

    __syncthreads();   // lut staged

    const int s_begin = w * 256;
    for (int sc = s_begin; sc < s_begin + 256; sc += 32) {
        float dA[4], dB[4];
#pragma unroll
        for (int reg = 0; reg < 4; ++reg) {
            const int t = t0 + 4 * g + reg;
            const size_t off = dbase + (size_t)t * Tc + sc + 2 * u;
            float2 d2 = *(const float2*)(rel + off);
            int2 m2 = *(const int2*)(msk + off);
            dA[reg] = m2.x ? -1.f : d2.x;
            dB[reg] = m2.y ? -1.f : d2.y;
        }
        float biasA[4][4], biasB[4][4];
#pragma unroll
        for (int reg = 0; reg < 4; ++reg) {
            int iA = (int)(dA[reg] * (float)LUTN);
            int iB = (int)(dB[reg] * (float)LUTN);
            iA = iA < 0 ? 0 : (iA > LUTN - 1 ? LUTN - 1 : iA);
            iB = iB < 0 ? 0 : (iB > LUTN - 1 ? LUTN - 1 : iB);
            uint4 wA = *(const uint4*)(lut_s + iA * 8);
            uint4 wB = *(const uint4*)(lut_s + iB * 8);
            biasA[reg][0] = fmaf(upk(wA.x), dA[reg], upkh(wA.x));
            biasA[reg][1] = fmaf(upk(wA.y), dA[reg], upkh(wA.y));
            biasA[reg][2] = fmaf(upk(wA.z), dA[reg], upkh(wA.z));
            biasA[reg][3] = fmaf(upk(wA.w), dA[reg], upkh(wA.w));
            biasB[reg][0] = fmaf(upk(wB.x), dB[reg], upkh(wB.x));
            biasB[reg][1] = fmaf(upk(wB.y), dB[reg], upkh(wB.y));
            biasB[reg][2] = fmaf(upk(wB.z), dB[reg], upkh(wB.z));
            biasB[reg][3] = fmaf(upk(wB.w), dB[reg], upkh(wB.w));
        }
        const size_t vtile = ((size_t)0 + (sc >> 5)) * 1024;   // per-head offset added below
#pragma unroll
        for (int hi = 0; hi < 4; ++hi) {
            const size_t kb = ((size_t)(bh0 + hi) * Tc + sc + 2 * u) * 32 + g * 8;
            short8 kfA = *(const short8*)(Kb + kb);
            short8 kfB = *(const short8*)(Kb + kb + 32);
            const f32x4 z4 = (f32x4){0.f, 0.f, 0.f, 0.f};
            f32x4 sA = __builtin_amdgcn_mfma_f32_16x16x32_bf16(qf[hi], kfA, z4, 0, 0, 0);
            f32x4 sB = __builtin_amdgcn_mfma_f32_16x16x32_bf16(qf[hi], kfB, z4, 0, 0, 0);
#pragma unroll
            for (int reg = 0; reg < 4; ++reg) {
                float zA = (dA[reg] < 0.f) ? 0.f : __expf(sA[reg] - biasA[reg][hi]);
                float zB = (dB[reg] < 0.f) ? 0.f : __expf(sB[reg] - biasB[reg][hi]);
                pwb[(4 * g + reg) * 20 + u] = pk2t(zA, zB);
            }
            short8 pf = *(const short8*)((const char*)pwb + u * 80 + g * 16);
            const ushort* vb = Vt + ((size_t)(bh0 + hi) * 32 + (sc >> 5)) * 1024;
            short8 vf0 = *(const short8*)(vb + u * 32 + g * 8);
            short8 vf1 = *(const short8*)(vb + 512 + u * 32 + g * 8);
            oacc[hi][0] = __builtin_amdgcn_mfma_f32_16x16x32_bf16(pf, vf0, oacc[hi][0], 0, 0, 0);
            oacc[hi][1] = __builtin_amdgcn_mfma_f32_16x16x32_bf16(pf, vf1, oacc[hi][1], 0, 0, 0);
            rsacc[hi]   = __builtin_amdgcn_mfma_f32_16x16x32_bf16(pf, ones, rsacc[hi], 0, 0, 0);
        }
        (void)vtile;
    }

    // rowsums already reduced by the ones-MFMA (all u columns equal)
#pragma unroll
    for (int hi = 0; hi < 4; ++hi)
        if (u == 0) {
#pragma unroll
            for (int reg = 0; reg < 4; ++reg)
                rs_s[(w * 4 + hi) * 16 + 4 * g + reg] = rsacc[hi][reg];
        }
#pragma unroll
    for (int hi = 0; hi < 4; ++hi)
#pragma unroll
        for (int vt = 0; vt < 2; ++vt)
#pragma unroll
            for (int reg = 0; reg < 4; ++reg)
                comb[w * 2176 + (4 * g + reg) * 136 + hi * 32 + vt * 16 + u] =
                    (ushort)pk2t(0.f, oacc[hi][vt][reg]) >> 0 ? (ushort)(__float_as_uint(oacc[hi][vt][reg]) >> 16) : (ushort)(__float_as_uint(oacc[hi][vt][reg]) >> 16);
    __syncthreads();

    // combine 4 waves, normalize, store bf16 Y
    const int tl = tid >> 4;
    const int f0 = (tid & 15) * 8;
    const int hl = f0 >> 5;
    float rstot = rs_s[(0 + hl) * 16 + tl] + rs_s[(4 + hl) * 16 + tl]
                + rs_s[(8 + hl) * 16 + tl] + rs_s[(12 + hl) * 16 + tl];
    float inv = 1.f / (rstot + 1e-5f);
    float o[8];
#pragma unroll
    for (int k = 0; k < 8; ++k) o[k] = 0.f;
#pragma unroll
    for (int ww = 0; ww < 4; ++ww) {
        uint4 pv = *(const uint4*)&comb[ww * 2176 + tl * 136 + f0];
        o[0] += upk(pv.x); o[1] += upkh(pv.x);
        o[2] += upk(pv.y); o[3] += upkh(pv.y);
        o[4] += upk(pv.z); o[5] += upkh(pv.z);
        o[6] += upk(pv.w); o[7] += upkh(pv.w);
    }
    uint4 pw;
    pw.x = pk2(o[0] * inv, o[1] * inv); pw.y = pk2(o[2] * inv, o[3] * inv);
    pw.z = pk2(o[4] * inv, o[5] * inv); pw.w = pk2(o[6] * inv, o[7] * inv);
    *(uint4*)(Yb + ((size_t)b * Tc + t0 + tl) * Dc + hg * 128 + f0) = pw;
}

// ---------------- K3/K4: direct-MFMA GEMM + bias (+lrelu) + residual + LN ---
// grid 256, block 256 = 4 waves; block = 16 rows x 256 cols (full row).
__global__ __launch_bounds__(256) void gemm_ln(
    const ushort* __restrict__ A, const ushort* __restrict__ W,
    const float* __restrict__ bias,
    const float* __restrict__ resF, const ushort* __restrict__ resB,
    const float* __restrict__ gam, const float* __restrict__ bet,
    float* __restrict__ outF, ushort* __restrict__ outB, int act)
{
    const int tid = threadIdx.x;
    const int w = tid >> 6;
    const int l = tid & 63;
    const int u = l & 15, g = l >> 4;
    const int rbase = blockIdx.x * 16;

    __shared__ float red1[64], red2[64];

    f32x4 acc[4];
#pragma unroll
    for (int nt = 0; nt < 4; ++nt) acc[nt] = (f32x4){0.f, 0.f, 0.f, 0.f};

    const ushort* arow = A + (size_t)(rbase + u) * 256 + g * 8;
#pragma unroll 2
    for (int k0 = 0; k0 < 256; k0 += 32) {
        short8 af = *(const short8*)(arow + k0);
#pragma unroll
        for (int nt = 0; nt < 4; ++nt) {
            short8 bfr = *(const short8*)(W + (size_t)(w * 64 + nt * 16 + u) * 256 + k0 + g * 8);
            acc[nt] = __builtin_amdgcn_mfma_f32_16x16x32_bf16(af, bfr, acc[nt], 0, 0, 0);
        }
    }

    float bv[4];
#pragma unroll
    for (int nt = 0; nt < 4; ++nt) bv[nt] = bias[w * 64 + nt * 16 + u];

    float sv[4][4];   // [reg][nt]
#pragma unroll
    for (int reg = 0; reg < 4; ++reg) {
        const int row = rbase + 4 * g + reg;
        float s1 = 0.f, s2 = 0.f;
#pragma unroll
        for (int nt = 0; nt < 4; ++nt) {
            const int col = w * 64 + nt * 16 + u;
            float v = acc[nt][reg] + bv[nt];
            if (act) v = v >= 0.f ? v : 0.01f * v;
            float res = resF ? resF[(size_t)row * 256 + col]
                             : upk((unsigned)resB[(size_t)row * 256 + col]);
            float s = v + res;
            sv[reg][nt] = s;
            s1 += s;
            s2 = fmaf(s, s, s2);
        }
        s1 += __shfl_xor(s1, 1, 64); s2 += __shfl_xor(s2, 1, 64);
        s1 += __shfl_xor(s1, 2, 64); s2 += __shfl_xor(s2, 2, 64);
        s1 += __shfl_xor(s1, 4, 64); s2 += __shfl_xor(s2, 4, 64);
        s1 += __shfl_xor(s1, 8, 64); s2 += __shfl_xor(s2, 8, 64);
        if (u == 0) { red1[w * 16 + 4 * g + reg] = s1; red2[w * 16 + 4 * g + reg] = s2; }
    }
    __syncthreads();

    float gv[4], btv[4];
#pragma unroll
    for (int nt = 0; nt < 4; ++nt) {
        gv[nt]  = gam[w * 64 + nt * 16 + u];
        btv[nt] = bet[w * 64 + nt * 16 + u];
    }
#pragma unroll
    for (int reg = 0; reg < 4; ++reg) {
        const int row = rbase + 4 * g + reg;
        const int rl = 4 * g + reg;
        float S1 = red1[rl] + red1[16 + rl] + red1[32 + rl] + red1[48 + rl];
        float S2 = red2[rl] + red2[16 + rl] + red2[32 + rl] + red2[48 + rl];
        float mu = S1 * (1.f / 256.f);
        float var = S2 * (1.f / 256.f) - mu * mu;
        float rsig = rsqrtf(var + 1e-5f);
#pragma unroll
        for (int nt = 0; nt < 4; ++nt) {
            const int col = w * 64 + nt * 16 + u;
            float o = (sv[reg][nt] - mu) * rsig * gv[nt] + btv[nt];
            if (outF) outF[(size_t)row * 256 + col] = o;
            else      outB[(size_t)row * 256 + col] = (ushort)bf16u(o);
        }
    }
}

extern "C" void kernel_launch(void* const* d_in, const int* in_sizes, int n_in,
                              void* d_out, int out_size, void* d_ws, size_t ws_size,
                              hipStream_t stream) {
    const float* x    = (const float*)d_in[0];
    const int*   mask = (const int*)d_in[1];
    const float* rel  = (const float*)d_in[2];
    const float* Wq   = (const float*)d_in[3];
    const float* Wk   = (const float*)d_in[4];
    const float* Wv   = (const float*)d_in[5];
    const float* pw1  = (const float*)d_in[6];
    const float* pb1  = (const float*)d_in[7];
    const float* pw2  = (const float*)d_in[8];
    const float* pb2  = (const float*)d_in[9];
    const float* Wo   = (const float*)d_in[10];
    const float* bo   = (const float*)d_in[11];
    const float* Wf   = (const float*)d_in[12];
    const float* bf   = (const float*)d_in[13];
    const float* g1   = (const float*)d_in[14];
    const float* be1  = (const float*)d_in[15];
    const float* g2   = (const float*)d_in[16];
    const float* be2  = (const float*)d_in[17];
    float* out = (float*)d_out;

    char* wsb = (char*)d_ws;
    ushort* Xc    = (ushort*)(wsb);                        // 2 MB
    ushort* Qb    = (ushort*)(wsb + (size_t)( 2 << 20));   // 2 MB
    ushort* Kb    = (ushort*)(wsb + (size_t)( 4 << 20));   // 2 MB
    ushort* Vt    = (ushort*)(wsb + (size_t)( 6 << 20));   // 2 MB (tile-major)
    ushort* Yb    = (ushort*)(wsb + (size_t)( 8 << 20));   // 2 MB
    ushort* Wqkvc = (ushort*)(wsb + (size_t)(10 << 20));   // 384 KB
    ushort* Woc   = (ushort*)(wsb + (size_t)(10 << 20) + (512 << 10));  // 128 KB
    ushort* Wfc   = (ushort*)(wsb + (size_t)(10 << 20) + (768 << 10));  // 128 KB
    ushort* LUTb  = (ushort*)(wsb + (size_t)(11 << 20));   // 8 KB
    ushort* ZZb   = (ushort*)(wsb + (size_t)(12 << 20));   // 2 MB

    cast_all<<<1345, 256, 0, stream>>>(x, Wq, Wk, Wv, Wo, Wf,
                                       pw1, pb1, pw2, pb2,
                                       Xc, Wqkvc, Woc, Wfc, LUTb);
    qkv_direct<<<dim3(256, 3), 256, 0, stream>>>(Xc, Wqkvc, Qb, Kb, Vt);
    attn_mfma<<<dim3(64, 4, 2), 256, 0, stream>>>(Qb, Kb, Vt, rel, mask, LUTb, Yb);
    gemm_ln<<<256, 256, 0, stream>>>(Yb, Woc, bo, x, nullptr, g1, be1,
                                     nullptr, ZZb, 0);
    gemm_ln<<<256, 256, 0, stream>>>(ZZb, Wfc, bf, nullptr, ZZb, g2, be2,
                                     out, nullptr, 1);
}